// Round 19
// baseline (247.787 us; speedup 1.0000x reference)
//
#include <hip/hip_runtime.h>
#include <hip/hip_bf16.h>
#include <math.h>

#define NN 100000
#define NEDGE 1600000
#define HIDF 128
#define NCLS 18
#define NGR 512
#define CHSZ 2048                     // edges per bin chunk
#define NBKT 391                      // ceil(NN/256) buckets of 256 nodes
#define SRCM 0x1FFFF                  // 17-bit src mask (NN < 2^17)

using bf16x8  = __attribute__((ext_vector_type(8))) short;   // 8 bf16 in 4 VGPRs
using ushort8 = __attribute__((ext_vector_type(8))) unsigned short;
using f32x4   = __attribute__((ext_vector_type(4))) float;
using f32x2   = __attribute__((ext_vector_type(2))) float;

__device__ __forceinline__ float b2f(unsigned short u) {
    return __uint_as_float(((unsigned)u) << 16);
}
__device__ __forceinline__ unsigned short f2b(float f) {   // round-to-nearest-even
    unsigned u = __float_as_uint(f);
    unsigned r = (u + 0x7fffu + ((u >> 16) & 1u)) >> 16;
    return (unsigned short)r;
}
__device__ __forceinline__ unsigned char f2fp8(float f) {  // f32 -> OCP e4m3 (HW cvt)
    int p = __builtin_amdgcn_cvt_pk_fp8_f32(f, f, 0, false);
    return (unsigned char)(p & 0xff);
}

// ---------------- phase 1: bin edges into 256-node buckets; 4-B bin records (dst_low8<<17 | src) ----------------
__global__ __launch_bounds__(256) void bin_kernel(const int* __restrict__ src,
                                                  const int* __restrict__ dst,
                                                  unsigned* __restrict__ recs_out,
                                                  int2* __restrict__ cando, int nE) {
    __shared__ int cnt[512];
    __shared__ int ssum[256];
    __shared__ unsigned recs[CHSZ];   // 8 KB
    int c = blockIdx.x;
    int t = threadIdx.x;
    cnt[t] = 0; cnt[t + 256] = 0;
    __syncthreads();
    int e0 = c * CHSZ;
    int nv = nE - e0; if (nv > CHSZ) nv = CHSZ;
    int s8[8], d8[8];
    #pragma unroll
    for (int i = 0; i < 8; i++) {
        int li = t + i * 256;
        bool ok = li < nv;
        s8[i] = ok ? src[e0 + li] : -1;
        d8[i] = ok ? dst[e0 + li] : -1;
        if (ok) atomicAdd(&cnt[d8[i] >> 8], 1);
    }
    __syncthreads();
    int a = cnt[2 * t], b_ = cnt[2 * t + 1];
    ssum[t] = a + b_;
    __syncthreads();
    for (int off = 1; off < 256; off <<= 1) {       // Hillis-Steele inclusive over 256 pair-sums
        int v = (t >= off) ? ssum[t - off] : 0;
        __syncthreads();
        ssum[t] += v;
        __syncthreads();
    }
    int excl = ssum[t] - (a + b_);
    if (2 * t < NBKT)     cando[(size_t)c * NBKT + 2 * t]     = make_int2(a, excl);
    if (2 * t + 1 < NBKT) cando[(size_t)c * NBKT + 2 * t + 1] = make_int2(b_, excl + a);
    __syncthreads();
    cnt[2 * t] = excl; cnt[2 * t + 1] = excl + a;    // reuse as cursors
    __syncthreads();
    #pragma unroll
    for (int i = 0; i < 8; i++) {
        if (d8[i] >= 0) {
            int pos = atomicAdd(&cnt[d8[i] >> 8], 1);
            recs[pos] = ((unsigned)(d8[i] & 255) << 17) | (unsigned)s8[i];
        }
    }
    __syncthreads();
    for (int j = t; j < nv; j += 256)
        recs_out[(size_t)e0 + j] = recs[j];          // fully coalesced 4B stores
}

// ---------------- per-bucket degree count + node prep + bucket totals (fused) ----------------
__global__ __launch_bounds__(512) void bucket_count_kernel(const unsigned* __restrict__ recs_bin,
                                                           const int2* __restrict__ cando,
                                                           int* __restrict__ cnt,
                                                           int* __restrict__ bktsum,
                                                           float* __restrict__ dinv,
                                                           float* __restrict__ selfw,
                                                           int nch, int n) {
    __shared__ int c256[256];
    __shared__ int wsum[4];
    int b = blockIdx.x;
    int t = threadIdx.x;
    if (t < 256) c256[t] = 0;
    __syncthreads();
    for (int c = t; c < nch; c += 512) {
        int2 co = cando[(size_t)c * NBKT + b];
        size_t base = (size_t)c * CHSZ + co.y;
        for (int k = 0; k < co.x; ++k) {
            unsigned rec = recs_bin[base + k];
            atomicAdd(&c256[rec >> 17], 1);         // dst_low8
        }
    }
    __syncthreads();
    int node = (b << 8) + t;
    int cv = 0;
    if (t < 256) {
        cv = c256[t];
        if (node < n) {
            cnt[node] = cv;
            float deg = (float)cv + 1.0f;   // +1 self loop
            dinv[node]  = rsqrtf(deg);
            selfw[node] = 1.0f / deg;
        }
    }
    if (t < 256) {
        int s = cv;
        #pragma unroll
        for (int off = 32; off > 0; off >>= 1) s += __shfl_down(s, off);
        if ((t & 63) == 0) wsum[t >> 6] = s;
    }
    __syncthreads();
    if (t == 0) bktsum[b] = wsum[0] + wsum[1] + wsum[2] + wsum[3];
}

// ---------------- scan of 391 bucket sums (one tiny block) ----------------
__global__ __launch_bounds__(512) void scan_bkt_kernel(const int* __restrict__ bktsum,
                                                       int* __restrict__ bktoff, int nb) {
    __shared__ int t512[512];
    int t = threadIdx.x;
    t512[t] = (t < nb) ? bktsum[t] : 0;
    __syncthreads();
    for (int off = 1; off < 512; off <<= 1) {
        int v = (t >= off) ? t512[t - off] : 0;
        __syncthreads();
        t512[t] += v;
        __syncthreads();
    }
    if (t < nb) bktoff[t] = (t == 0) ? 0 : t512[t - 1];
}

// ---------------- phase 2: per-bucket CSR fill (8-B records {f32 w, src}) + rowptr ----------------
__global__ __launch_bounds__(512) void bucket_fill_kernel(const unsigned* __restrict__ recs_bin,
                                                          const int2* __restrict__ cando,
                                                          const int* __restrict__ cnt,
                                                          const int* __restrict__ bktoff,
                                                          const float* __restrict__ dinv,
                                                          int* __restrict__ rowptr,
                                                          long long* __restrict__ csr_rec,
                                                          int nch, int n, int nE) {
    __shared__ int cur[256];
    __shared__ int scn[256];
    int b = blockIdx.x;
    int node0 = b << 8;
    int t = threadIdx.x;
    int cv = 0;
    if (t < 256) {
        int nd = node0 + t;
        cv = (nd < n) ? cnt[nd] : 0;
        scn[t] = cv;
    }
    __syncthreads();
    for (int off = 1; off < 256; off <<= 1) {     // inclusive scan over this bucket's 256 counts
        int v = (t < 256 && t >= off) ? scn[t - off] : 0;
        __syncthreads();
        if (t < 256) scn[t] += v;
        __syncthreads();
    }
    if (t < 256) {
        int nd = node0 + t;
        int excl = bktoff[b] + scn[t] - cv;       // exclusive prefix = global row start
        if (nd < n) { rowptr[nd] = excl; cur[t] = excl; }
    }
    if (b == NBKT - 1 && t == 0) rowptr[n] = nE;
    __syncthreads();
    for (int c = t; c < nch; c += 512) {
        int2 co = cando[(size_t)c * NBKT + b];
        size_t base = (size_t)c * CHSZ + co.y;
        for (int k = 0; k < co.x; ++k) {
            unsigned rec = recs_bin[base + k];
            int dlow = rec >> 17;
            int s = rec & SRCM;
            int d = node0 + dlow;
            float w = dinv[s] * dinv[d];
            int pos = atomicAdd(&cur[dlow], 1);
            csr_rec[pos] = ((long long)__float_as_int(w) << 32) | (unsigned)s;
        }
    }
}

// ---------------- weight prep: pack W (f32 row-major 128x128) into B-fragment-linear bf16 ----------------
__global__ __launch_bounds__(256) void wprep_kernel(const float* __restrict__ W1,
                                                    const float* __restrict__ W2,
                                                    const float* __restrict__ W3,
                                                    unsigned short* __restrict__ Wf) {
    int gid = blockIdx.x * 256 + threadIdx.x;   // 0..49151
    int w = gid >> 14;
    int o = gid & 16383;
    int j = o & 7, lane = (o >> 3) & 63, ct = (o >> 9) & 7, kt = o >> 12;
    int rk = kt * 32 + (lane >> 4) * 8 + j;
    int col = ct * 16 + (lane & 15);
    const float* W = (w == 0) ? W1 : ((w == 1) ? W2 : W3);
    Wf[gid] = f2b(W[rk * HIDF + col]);
}

// ---------------- MFMA GEMM (layer 1): Hfp8 = x @ W1  (f32 in, fp8 out) ----------------
__global__ __launch_bounds__(256) void mfma_gemm_kernel(const float* __restrict__ X,
                                                        const unsigned short* __restrict__ Wfrag,
                                                        unsigned char* __restrict__ Hfp8, int n) {
    __shared__ unsigned short wl[16384];   // 32 KB: full 128x128 bf16 W in fragment-linear layout
    {
        const uint4* wsrc = reinterpret_cast<const uint4*>(Wfrag);
        uint4* wdst = reinterpret_cast<uint4*>(wl);
        for (int i = threadIdx.x; i < 2048; i += 256) wdst[i] = wsrc[i];
    }
    __syncthreads();

    int wv = threadIdx.x >> 6;          // wave 0..3
    int l  = threadIdx.x & 63;          // lane
    int row = blockIdx.x * 64 + wv * 16 + (l & 15);
    int koff = (l >> 4) * 8;
    bool rowok = row < n;

    f32x4 acc[8] = {};
    #pragma unroll
    for (int kt = 0; kt < 4; ++kt) {
        int kbase = kt * 32 + koff;
        bf16x8 a;
        float4 x0 = {0,0,0,0}, x1 = {0,0,0,0};
        if (rowok) {
            x0 = *reinterpret_cast<const float4*>(&X[(size_t)row * HIDF + kbase]);
            x1 = *reinterpret_cast<const float4*>(&X[(size_t)row * HIDF + kbase + 4]);
        }
        a[0] = (short)f2b(x0.x); a[1] = (short)f2b(x0.y);
        a[2] = (short)f2b(x0.z); a[3] = (short)f2b(x0.w);
        a[4] = (short)f2b(x1.x); a[5] = (short)f2b(x1.y);
        a[6] = (short)f2b(x1.z); a[7] = (short)f2b(x1.w);
        #pragma unroll
        for (int ct = 0; ct < 8; ++ct) {
            bf16x8 b = *reinterpret_cast<bf16x8*>(&wl[((kt * 8 + ct) * 64 + l) * 8]);
            acc[ct] = __builtin_amdgcn_mfma_f32_16x16x32_bf16(a, b, acc[ct], 0, 0, 0);
        }
    }
    int rbase = blockIdx.x * 64 + wv * 16 + ((l >> 4) << 2);
    int cbase = l & 15;
    #pragma unroll
    for (int ct = 0; ct < 8; ++ct) {
        #pragma unroll
        for (int r = 0; r < 4; ++r) {
            int gr = rbase + r;
            if (gr < n) Hfp8[(size_t)gr * HIDF + ct * 16 + cbase] = f2fp8(acc[ct][r]);
        }
    }
}

// ---------------- FUSED gather + next-layer GEMM (256 thr, 32 nodes/block, W from L2) ----------------
__global__ __launch_bounds__(256) void fused_gather_gemm_kernel(
        const unsigned char* __restrict__ Hin,
        const int* __restrict__ rowptr,
        const long long* __restrict__ csr_rec,
        const float* __restrict__ selfw,
        const float* __restrict__ bias,
        const unsigned short* __restrict__ Wfrag,
        unsigned char* __restrict__ Hout, int n) {
    __shared__ unsigned short agg[32][136];  // 32 rows x 128 bf16, +8 pad (8.7 KB)
    int node0 = blockIdx.x * 32;
    int nl   = threadIdx.x >> 3;         // node-local 0..31
    int node = node0 + nl;
    int lane = threadIdx.x & 7;          // feature segment [lane*16, lane*16+16)
    if (node < n) {
        float acc[16];
        {
            uint4 sv = *reinterpret_cast<const uint4*>(Hin + (size_t)node * HIDF + lane * 16);
            const unsigned* svw = reinterpret_cast<const unsigned*>(&sv);
            float sw = selfw[node];
            #pragma unroll
            for (int d = 0; d < 4; ++d) {
                f32x2 lo = __builtin_amdgcn_cvt_pk_f32_fp8((int)svw[d], false);
                f32x2 hi = __builtin_amdgcn_cvt_pk_f32_fp8((int)svw[d], true);
                acc[d * 4 + 0] = lo[0] * sw; acc[d * 4 + 1] = lo[1] * sw;
                acc[d * 4 + 2] = hi[0] * sw; acc[d * 4 + 3] = hi[1] * sw;
            }
        }
        int beg = rowptr[node], end = rowptr[node + 1];
        int nfull = (end - beg) >> 3;
        int base = beg;
        for (int fb = 0; fb < nfull; ++fb, base += 8) {
            long long rec = csr_rec[base + lane];
            uint4 v[8];
            float w[8];
            #pragma unroll
            for (int j = 0; j < 8; ++j) {                    // 8 independent row loads in flight
                long long r = __shfl(rec, j, 8);
                int sn = (int)(unsigned)(r & 0xffffffffLL);
                w[j] = __int_as_float((int)(r >> 32));
                v[j] = *reinterpret_cast<const uint4*>(Hin + (size_t)sn * HIDF + lane * 16);
            }
            #pragma unroll
            for (int j = 0; j < 8; ++j) {
                const unsigned* vw = reinterpret_cast<const unsigned*>(&v[j]);
                #pragma unroll
                for (int d = 0; d < 4; ++d) {
                    f32x2 lo = __builtin_amdgcn_cvt_pk_f32_fp8((int)vw[d], false);
                    f32x2 hi = __builtin_amdgcn_cvt_pk_f32_fp8((int)vw[d], true);
                    acc[d * 4 + 0] += lo[0] * w[j]; acc[d * 4 + 1] += lo[1] * w[j];
                    acc[d * 4 + 2] += hi[0] * w[j]; acc[d * 4 + 3] += hi[1] * w[j];
                }
            }
        }
        int m = end - base;
        if (m > 0) {
            long long rec = (base + lane < end) ? csr_rec[base + lane] : 0;
            for (int j = 0; j < m; ++j) {
                long long r = __shfl(rec, j, 8);
                int sn = (int)(unsigned)(r & 0xffffffffLL);
                float w = __int_as_float((int)(r >> 32));
                uint4 v = *reinterpret_cast<const uint4*>(Hin + (size_t)sn * HIDF + lane * 16);
                const unsigned* vw = reinterpret_cast<const unsigned*>(&v);
                #pragma unroll
                for (int d = 0; d < 4; ++d) {
                    f32x2 lo = __builtin_amdgcn_cvt_pk_f32_fp8((int)vw[d], false);
                    f32x2 hi = __builtin_amdgcn_cvt_pk_f32_fp8((int)vw[d], true);
                    acc[d * 4 + 0] += lo[0] * w; acc[d * 4 + 1] += lo[1] * w;
                    acc[d * 4 + 2] += hi[0] * w; acc[d * 4 + 3] += hi[1] * w;
                }
            }
        }
        // bias + relu (f32, single round) -> bf16 A-tile
        #pragma unroll
        for (int i = 0; i < 16; ++i) {
            float vb = acc[i] + bias[lane * 16 + i];
            agg[nl][lane * 16 + i] = f2b(fmaxf(vb, 0.f));
        }
    } else {
        #pragma unroll
        for (int i = 0; i < 16; ++i) agg[nl][lane * 16 + i] = 0;
    }
    __syncthreads();
    // Phase B: MFMA over 32x128 tile. wave wv: row tile mt = wv>>1 (16 rows), col tiles ct0..ct0+3
    int wv = threadIdx.x >> 6;
    int l  = threadIdx.x & 63;
    int mt  = wv >> 1;                   // 0..1
    int ct0 = (wv & 1) * 4;
    int arow = mt * 16 + (l & 15);
    int koff = (l >> 4) * 8;
    f32x4 acc4[4] = {};
    #pragma unroll
    for (int kt = 0; kt < 4; ++kt) {
        int kbase = kt * 32 + koff;
        bf16x8 a = *reinterpret_cast<bf16x8*>(&agg[arow][kbase]);
        #pragma unroll
        for (int c = 0; c < 4; ++c) {
            int ct = ct0 + c;
            bf16x8 b = *reinterpret_cast<const bf16x8*>(&Wfrag[((kt * 8 + ct) * 64 + l) * 8]);
            acc4[c] = __builtin_amdgcn_mfma_f32_16x16x32_bf16(a, b, acc4[c], 0, 0, 0);
        }
    }
    int rloc = mt * 16 + ((l >> 4) << 2);
    int cbase = l & 15;
    #pragma unroll
    for (int c = 0; c < 4; ++c) {
        int ct = ct0 + c;
        #pragma unroll
        for (int r = 0; r < 4; ++r) {
            int gr = node0 + rloc + r;
            if (gr < n) Hout[(size_t)gr * HIDF + ct * 16 + cbase] = f2fp8(acc4[c][r]);
        }
    }
}

// ---------------- final gather + pool partials: 4 blocks per graph (deterministic, no atomics) ----------------
__device__ __forceinline__ int lower_bound_i(const int* __restrict__ a, int n, int key) {
    int lo = 0, hi = n;
    while (lo < hi) { int mid = (lo + hi) >> 1; if (a[mid] < key) lo = mid + 1; else hi = mid; }
    return lo;
}

__global__ __launch_bounds__(256) void gather_pool_partial_kernel(
        const unsigned char* __restrict__ Hin,
        const int* __restrict__ rowptr,
        const long long* __restrict__ csr_rec,
        const float* __restrict__ selfw,
        const int* __restrict__ batch,
        float* __restrict__ gpart, int n) {
    __shared__ float part[32][HIDF];   // 16 KB
    int b = blockIdx.x >> 2;
    int c = blockIdx.x & 3;
    int grp  = threadIdx.x >> 3;       // group 0..31
    int lane = threadIdx.x & 7;        // feature segment [lane*16, lane*16+16)
    int s = lower_bound_i(batch, n, b);
    int e = lower_bound_i(batch, n, b + 1);
    float acc[16];
    #pragma unroll
    for (int i = 0; i < 16; ++i) acc[i] = 0.f;
    for (int node = s + c * 32 + grp; node < e; node += 128) {
        float t[16];
        {
            uint4 sv = *reinterpret_cast<const uint4*>(Hin + (size_t)node * HIDF + lane * 16);
            const unsigned* svw = reinterpret_cast<const unsigned*>(&sv);
            float sw = selfw[node];
            #pragma unroll
            for (int d = 0; d < 4; ++d) {
                f32x2 lo = __builtin_amdgcn_cvt_pk_f32_fp8((int)svw[d], false);
                f32x2 hi = __builtin_amdgcn_cvt_pk_f32_fp8((int)svw[d], true);
                t[d * 4 + 0] = lo[0] * sw; t[d * 4 + 1] = lo[1] * sw;
                t[d * 4 + 2] = hi[0] * sw; t[d * 4 + 3] = hi[1] * sw;
            }
        }
        int beg = rowptr[node], end = rowptr[node + 1];
        int nfull = (end - beg) >> 3;
        int base = beg;
        for (int fb = 0; fb < nfull; ++fb, base += 8) {
            long long rec = csr_rec[base + lane];
            uint4 v[8];
            float w[8];
            #pragma unroll
            for (int j = 0; j < 8; ++j) {
                long long r = __shfl(rec, j, 8);
                int sn = (int)(unsigned)(r & 0xffffffffLL);
                w[j] = __int_as_float((int)(r >> 32));
                v[j] = *reinterpret_cast<const uint4*>(Hin + (size_t)sn * HIDF + lane * 16);
            }
            #pragma unroll
            for (int j = 0; j < 8; ++j) {
                const unsigned* vw = reinterpret_cast<const unsigned*>(&v[j]);
                #pragma unroll
                for (int d = 0; d < 4; ++d) {
                    f32x2 lo = __builtin_amdgcn_cvt_pk_f32_fp8((int)vw[d], false);
                    f32x2 hi = __builtin_amdgcn_cvt_pk_f32_fp8((int)vw[d], true);
                    t[d * 4 + 0] += lo[0] * w[j]; t[d * 4 + 1] += lo[1] * w[j];
                    t[d * 4 + 2] += hi[0] * w[j]; t[d * 4 + 3] += hi[1] * w[j];
                }
            }
        }
        int m = end - base;
        if (m > 0) {
            long long rec = (base + lane < end) ? csr_rec[base + lane] : 0;
            for (int j = 0; j < m; ++j) {
                long long r = __shfl(rec, j, 8);
                int sn = (int)(unsigned)(r & 0xffffffffLL);
                float w = __int_as_float((int)(r >> 32));
                uint4 v = *reinterpret_cast<const uint4*>(Hin + (size_t)sn * HIDF + lane * 16);
                const unsigned* vw = reinterpret_cast<const unsigned*>(&v);
                #pragma unroll
                for (int d = 0; d < 4; ++d) {
                    f32x2 lo = __builtin_amdgcn_cvt_pk_f32_fp8((int)vw[d], false);
                    f32x2 hi = __builtin_amdgcn_cvt_pk_f32_fp8((int)vw[d], true);
                    t[d * 4 + 0] += lo[0] * w; t[d * 4 + 1] += lo[1] * w;
                    t[d * 4 + 2] += hi[0] * w; t[d * 4 + 3] += hi[1] * w;
                }
            }
        }
        #pragma unroll
        for (int i = 0; i < 16; ++i) acc[i] += t[i];
    }
    #pragma unroll
    for (int i = 0; i < 16; ++i) part[grp][lane * 16 + i] = acc[i];
    __syncthreads();
    if (threadIdx.x < HIDF) {
        int f = threadIdx.x;
        float sum = 0.f;
        #pragma unroll 8
        for (int g = 0; g < 32; ++g) sum += part[g][f];
        gpart[(size_t)blockIdx.x * HIDF + f] = sum;
    }
}

// ---------------- head: combine 4 partials -> mean (+b3) -> centroid head ----------------
__global__ __launch_bounds__(64) void head_kernel(const float* __restrict__ gpart,
                                                  const int* __restrict__ batch,
                                                  const float* __restrict__ b3,
                                                  const float* __restrict__ centroids,
                                                  const float* __restrict__ std_scale,
                                                  const float* __restrict__ ac_temp,
                                                  float* __restrict__ out, int n) {
    int b = blockIdx.x;
    int l = threadIdx.x;
    int s = lower_bound_i(batch, n, b);
    int e = lower_bound_i(batch, n, b + 1);
    float cnt = fmaxf((float)(e - s), 1.0f);
    float inv = 1.0f / cnt;
    const float* gp = gpart + (size_t)b * 4 * HIDF;
    float g0 = (gp[l]        + gp[HIDF + l]        + gp[2*HIDF + l]        + gp[3*HIDF + l])        * inv + b3[l];
    float g1 = (gp[64 + l]   + gp[HIDF + 64 + l]   + gp[2*HIDF + 64 + l]   + gp[3*HIDF + 64 + l])   * inv + b3[64 + l];
    float mind = 1e30f;
    for (int c = 0; c < NCLS; ++c) {
        float dd[2];
        #pragma unroll
        for (int cent = 0; cent < 2; ++cent) {
            const float* cp = &centroids[(c * 2 + cent) * HIDF];
            float df0 = cp[l] - g0;
            float df1 = cp[64 + l] - g1;
            float p = df0 * df0 + df1 * df1;
            #pragma unroll
            for (int off = 32; off > 0; off >>= 1) p += __shfl_xor(p, off);
            dd[cent] = p;
        }
        float dist = fminf(sqrtf(dd[0]), sqrtf(dd[1]));
        mind = fminf(mind, dist);
        if (l == 0) out[b * NCLS + c] = -dist;
    }
    if (l == 0) {
        float ss = std_scale[0];
        float clipped = fminf(fmaxf(ss, 0.0f), 5.0f);
        float max_ac = 1.0f + clipped * 0.0f;      // RUNNING_MEAN=1, sqrt(RUNNING_VAR)=0
        float accept = max_ac - mind;
        float soft = 1.0f / (1.0f + expf(-accept / ac_temp[0]));
        out[NGR * NCLS + b] = soft;
    }
}

// ---------------- launch ----------------
extern "C" void kernel_launch(void* const* d_in, const int* in_sizes, int n_in,
                              void* d_out, int out_size, void* d_ws, size_t ws_size,
                              hipStream_t stream) {
    const float* x         = (const float*)d_in[0];
    const int*   edge      = (const int*)d_in[1];
    const int*   batch     = (const int*)d_in[2];
    const float* W1        = (const float*)d_in[3];
    const float* b1        = (const float*)d_in[4];
    const float* W2        = (const float*)d_in[5];
    const float* b2        = (const float*)d_in[6];
    const float* W3        = (const float*)d_in[7];
    const float* b3        = (const float*)d_in[8];
    const float* centroids = (const float*)d_in[9];
    const float* std_scale = (const float*)d_in[10];
    const float* ac_temp   = (const float*)d_in[11];
    float* out = (float*)d_out;

    const int n  = NN;
    const int nE = in_sizes[1] / 2;
    const int* srcp = edge;
    const int* dstp = edge + nE;
    const int nch = (nE + CHSZ - 1) / CHSZ;

    // workspace layout (256B aligned)
    char* ws = (char*)d_ws;
    size_t off = 0;
    auto alloc = [&](size_t bytes) { void* p = ws + off; off = (off + bytes + 255) & ~(size_t)255; return p; };
    unsigned char*  hP = (unsigned char*) alloc((size_t)NN * HIDF);      // fp8 table (ping)
    unsigned char*  hQ = (unsigned char*) alloc((size_t)NN * HIDF);      // fp8 table (pong)
    unsigned short* Wf = (unsigned short*)alloc((size_t)3 * HIDF * HIDF * 2);
    float* dinv    = (float*)alloc((size_t)NN * 4);
    float* selfw   = (float*)alloc((size_t)NN * 4);
    int*   cnt     = (int*)  alloc((size_t)NN * 4);
    int*   rowptr  = (int*)  alloc((size_t)(NN + 1) * 4);
    long long* csr_rec  = (long long*)alloc((size_t)nE * 8);
    unsigned*  recs_bin = (unsigned*) alloc((size_t)nE * 4);
    int2*  cando   = (int2*) alloc((size_t)nch * NBKT * 8);
    int*   bktsum  = (int*)  alloc((size_t)NBKT * 4);
    int*   bktoff  = (int*)  alloc((size_t)NBKT * 4);
    float* gpart   = (float*)alloc((size_t)NGR * 4 * HIDF * 4);

    // ---- weight prep + CSR build (CSR reused by all 3 layers) ----
    wprep_kernel<<<192, 256, 0, stream>>>(W1, W2, W3, Wf);
    bin_kernel<<<nch, 256, 0, stream>>>(srcp, dstp, recs_bin, cando, nE);
    bucket_count_kernel<<<NBKT, 512, 0, stream>>>(recs_bin, cando, cnt, bktsum, dinv, selfw, nch, n);
    scan_bkt_kernel<<<1, 512, 0, stream>>>(bktsum, bktoff, NBKT);
    bucket_fill_kernel<<<NBKT, 512, 0, stream>>>(recs_bin, cando, cnt, bktoff, dinv, rowptr, csr_rec, nch, n, nE);

    int gemm_blocks  = (n + 63) / 64;
    int fused_blocks = (n + 31) / 32;

    // layer 1 GEMM: x @ W1 -> hP (fp8)
    mfma_gemm_kernel<<<gemm_blocks, 256, 0, stream>>>(x, Wf, hP, n);
    // fused: gather(hP) -> +b1,relu -> @W2 -> hQ (fp8)
    fused_gather_gemm_kernel<<<fused_blocks, 256, 0, stream>>>(hP, rowptr, csr_rec, selfw, b1, Wf + 16384, hQ, n);
    // fused: gather(hQ) -> +b2,relu -> @W3 -> hP (fp8)
    fused_gather_gemm_kernel<<<fused_blocks, 256, 0, stream>>>(hQ, rowptr, csr_rec, selfw, b2, Wf + 32768, hP, n);
    // final gather + pool partials (4 blocks/graph), then head
    gather_pool_partial_kernel<<<NGR * 4, 256, 0, stream>>>(hP, rowptr, csr_rec, selfw, batch, gpart, n);
    head_kernel<<<NGR, 64, 0, stream>>>(gpart, batch, b3, centroids, std_scale, ac_temp, out, n);
}

// Round 20
// 226.097 us; speedup vs baseline: 1.0959x; 1.0959x over previous
//
#include <hip/hip_runtime.h>
#include <hip/hip_bf16.h>
#include <math.h>

#define NN 100000
#define NEDGE 1600000
#define HIDF 128
#define NCLS 18
#define NGR 512
#define CHSZ 2048                     // edges per bin chunk
#define NBKT 391                      // ceil(NN/256) buckets of 256 nodes
#define SRCM 0x1FFFF                  // 17-bit src mask (NN < 2^17)

using bf16x8  = __attribute__((ext_vector_type(8))) short;   // 8 bf16 in 4 VGPRs
using ushort8 = __attribute__((ext_vector_type(8))) unsigned short;
using f32x4   = __attribute__((ext_vector_type(4))) float;
using f32x2   = __attribute__((ext_vector_type(2))) float;

__device__ __forceinline__ float b2f(unsigned short u) {
    return __uint_as_float(((unsigned)u) << 16);
}
__device__ __forceinline__ unsigned short f2b(float f) {   // round-to-nearest-even
    unsigned u = __float_as_uint(f);
    unsigned r = (u + 0x7fffu + ((u >> 16) & 1u)) >> 16;
    return (unsigned short)r;
}
__device__ __forceinline__ unsigned char f2fp8(float f) {  // f32 -> OCP e4m3 (HW cvt)
    int p = __builtin_amdgcn_cvt_pk_fp8_f32(f, f, 0, false);
    return (unsigned char)(p & 0xff);
}

// ---------------- phase 1: bin edges into 256-node buckets; 4-B bin records (dst_low8<<17 | src) ----------------
__global__ __launch_bounds__(256) void bin_kernel(const int* __restrict__ src,
                                                  const int* __restrict__ dst,
                                                  unsigned* __restrict__ recs_out,
                                                  int2* __restrict__ cando, int nE) {
    __shared__ int cnt[512];
    __shared__ int ssum[256];
    __shared__ unsigned recs[CHSZ];   // 8 KB
    int c = blockIdx.x;
    int t = threadIdx.x;
    cnt[t] = 0; cnt[t + 256] = 0;
    __syncthreads();
    int e0 = c * CHSZ;
    int nv = nE - e0; if (nv > CHSZ) nv = CHSZ;
    int s8[8], d8[8];
    #pragma unroll
    for (int i = 0; i < 8; i++) {
        int li = t + i * 256;
        bool ok = li < nv;
        s8[i] = ok ? src[e0 + li] : -1;
        d8[i] = ok ? dst[e0 + li] : -1;
        if (ok) atomicAdd(&cnt[d8[i] >> 8], 1);
    }
    __syncthreads();
    int a = cnt[2 * t], b_ = cnt[2 * t + 1];
    ssum[t] = a + b_;
    __syncthreads();
    for (int off = 1; off < 256; off <<= 1) {       // Hillis-Steele inclusive over 256 pair-sums
        int v = (t >= off) ? ssum[t - off] : 0;
        __syncthreads();
        ssum[t] += v;
        __syncthreads();
    }
    int excl = ssum[t] - (a + b_);
    if (2 * t < NBKT)     cando[(size_t)c * NBKT + 2 * t]     = make_int2(a, excl);
    if (2 * t + 1 < NBKT) cando[(size_t)c * NBKT + 2 * t + 1] = make_int2(b_, excl + a);
    __syncthreads();
    cnt[2 * t] = excl; cnt[2 * t + 1] = excl + a;    // reuse as cursors
    __syncthreads();
    #pragma unroll
    for (int i = 0; i < 8; i++) {
        if (d8[i] >= 0) {
            int pos = atomicAdd(&cnt[d8[i] >> 8], 1);
            recs[pos] = ((unsigned)(d8[i] & 255) << 17) | (unsigned)s8[i];
        }
    }
    __syncthreads();
    for (int j = t; j < nv; j += 256)
        recs_out[(size_t)e0 + j] = recs[j];          // fully coalesced 4B stores
}

// ---------------- per-bucket degree count + node prep + bucket totals (fused) ----------------
__global__ __launch_bounds__(512) void bucket_count_kernel(const unsigned* __restrict__ recs_bin,
                                                           const int2* __restrict__ cando,
                                                           int* __restrict__ cnt,
                                                           int* __restrict__ bktsum,
                                                           float* __restrict__ dinv,
                                                           float* __restrict__ selfw,
                                                           int nch, int n) {
    __shared__ int c256[256];
    __shared__ int wsum[4];
    int b = blockIdx.x;
    int t = threadIdx.x;
    if (t < 256) c256[t] = 0;
    __syncthreads();
    for (int c = t; c < nch; c += 512) {
        int2 co = cando[(size_t)c * NBKT + b];
        size_t base = (size_t)c * CHSZ + co.y;
        for (int k = 0; k < co.x; ++k) {
            unsigned rec = recs_bin[base + k];
            atomicAdd(&c256[rec >> 17], 1);         // dst_low8
        }
    }
    __syncthreads();
    int node = (b << 8) + t;
    int cv = 0;
    if (t < 256) {
        cv = c256[t];
        if (node < n) {
            cnt[node] = cv;
            float deg = (float)cv + 1.0f;   // +1 self loop
            dinv[node]  = rsqrtf(deg);
            selfw[node] = 1.0f / deg;
        }
    }
    if (t < 256) {
        int s = cv;
        #pragma unroll
        for (int off = 32; off > 0; off >>= 1) s += __shfl_down(s, off);
        if ((t & 63) == 0) wsum[t >> 6] = s;
    }
    __syncthreads();
    if (t == 0) bktsum[b] = wsum[0] + wsum[1] + wsum[2] + wsum[3];
}

// ---------------- scan of 391 bucket sums (one tiny block) ----------------
__global__ __launch_bounds__(512) void scan_bkt_kernel(const int* __restrict__ bktsum,
                                                       int* __restrict__ bktoff, int nb) {
    __shared__ int t512[512];
    int t = threadIdx.x;
    t512[t] = (t < nb) ? bktsum[t] : 0;
    __syncthreads();
    for (int off = 1; off < 512; off <<= 1) {
        int v = (t >= off) ? t512[t - off] : 0;
        __syncthreads();
        t512[t] += v;
        __syncthreads();
    }
    if (t < nb) bktoff[t] = (t == 0) ? 0 : t512[t - 1];
}

// ---------------- phase 2: per-bucket CSR fill (8-B records {f32 w, src}) + rowptr ----------------
__global__ __launch_bounds__(512) void bucket_fill_kernel(const unsigned* __restrict__ recs_bin,
                                                          const int2* __restrict__ cando,
                                                          const int* __restrict__ cnt,
                                                          const int* __restrict__ bktoff,
                                                          const float* __restrict__ dinv,
                                                          int* __restrict__ rowptr,
                                                          long long* __restrict__ csr_rec,
                                                          int nch, int n, int nE) {
    __shared__ int cur[256];
    __shared__ int scn[256];
    int b = blockIdx.x;
    int node0 = b << 8;
    int t = threadIdx.x;
    int cv = 0;
    if (t < 256) {
        int nd = node0 + t;
        cv = (nd < n) ? cnt[nd] : 0;
        scn[t] = cv;
    }
    __syncthreads();
    for (int off = 1; off < 256; off <<= 1) {     // inclusive scan over this bucket's 256 counts
        int v = (t < 256 && t >= off) ? scn[t - off] : 0;
        __syncthreads();
        if (t < 256) scn[t] += v;
        __syncthreads();
    }
    if (t < 256) {
        int nd = node0 + t;
        int excl = bktoff[b] + scn[t] - cv;       // exclusive prefix = global row start
        if (nd < n) { rowptr[nd] = excl; cur[t] = excl; }
    }
    if (b == NBKT - 1 && t == 0) rowptr[n] = nE;
    __syncthreads();
    for (int c = t; c < nch; c += 512) {
        int2 co = cando[(size_t)c * NBKT + b];
        size_t base = (size_t)c * CHSZ + co.y;
        for (int k = 0; k < co.x; ++k) {
            unsigned rec = recs_bin[base + k];
            int dlow = rec >> 17;
            int s = rec & SRCM;
            int d = node0 + dlow;
            float w = dinv[s] * dinv[d];
            int pos = atomicAdd(&cur[dlow], 1);
            csr_rec[pos] = ((long long)__float_as_int(w) << 32) | (unsigned)s;
        }
    }
}

// ---------------- weight prep: pack W (f32 row-major 128x128) into B-fragment-linear bf16 ----------------
__global__ __launch_bounds__(256) void wprep_kernel(const float* __restrict__ W1,
                                                    const float* __restrict__ W2,
                                                    const float* __restrict__ W3,
                                                    unsigned short* __restrict__ Wf) {
    int gid = blockIdx.x * 256 + threadIdx.x;   // 0..49151
    int w = gid >> 14;
    int o = gid & 16383;
    int j = o & 7, lane = (o >> 3) & 63, ct = (o >> 9) & 7, kt = o >> 12;
    int rk = kt * 32 + (lane >> 4) * 8 + j;
    int col = ct * 16 + (lane & 15);
    const float* W = (w == 0) ? W1 : ((w == 1) ? W2 : W3);
    Wf[gid] = f2b(W[rk * HIDF + col]);
}

// ---------------- MFMA GEMM (layer 1): Hfp8 = x @ W1  (f32 in, fp8 out) ----------------
__global__ __launch_bounds__(256) void mfma_gemm_kernel(const float* __restrict__ X,
                                                        const unsigned short* __restrict__ Wfrag,
                                                        unsigned char* __restrict__ Hfp8, int n) {
    __shared__ unsigned short wl[16384];   // 32 KB: full 128x128 bf16 W in fragment-linear layout
    {
        const uint4* wsrc = reinterpret_cast<const uint4*>(Wfrag);
        uint4* wdst = reinterpret_cast<uint4*>(wl);
        for (int i = threadIdx.x; i < 2048; i += 256) wdst[i] = wsrc[i];
    }
    __syncthreads();

    int wv = threadIdx.x >> 6;          // wave 0..3
    int l  = threadIdx.x & 63;          // lane
    int row = blockIdx.x * 64 + wv * 16 + (l & 15);
    int koff = (l >> 4) * 8;
    bool rowok = row < n;

    f32x4 acc[8] = {};
    #pragma unroll
    for (int kt = 0; kt < 4; ++kt) {
        int kbase = kt * 32 + koff;
        bf16x8 a;
        float4 x0 = {0,0,0,0}, x1 = {0,0,0,0};
        if (rowok) {
            x0 = *reinterpret_cast<const float4*>(&X[(size_t)row * HIDF + kbase]);
            x1 = *reinterpret_cast<const float4*>(&X[(size_t)row * HIDF + kbase + 4]);
        }
        a[0] = (short)f2b(x0.x); a[1] = (short)f2b(x0.y);
        a[2] = (short)f2b(x0.z); a[3] = (short)f2b(x0.w);
        a[4] = (short)f2b(x1.x); a[5] = (short)f2b(x1.y);
        a[6] = (short)f2b(x1.z); a[7] = (short)f2b(x1.w);
        #pragma unroll
        for (int ct = 0; ct < 8; ++ct) {
            bf16x8 b = *reinterpret_cast<bf16x8*>(&wl[((kt * 8 + ct) * 64 + l) * 8]);
            acc[ct] = __builtin_amdgcn_mfma_f32_16x16x32_bf16(a, b, acc[ct], 0, 0, 0);
        }
    }
    int rbase = blockIdx.x * 64 + wv * 16 + ((l >> 4) << 2);
    int cbase = l & 15;
    #pragma unroll
    for (int ct = 0; ct < 8; ++ct) {
        #pragma unroll
        for (int r = 0; r < 4; ++r) {
            int gr = rbase + r;
            if (gr < n) Hfp8[(size_t)gr * HIDF + ct * 16 + cbase] = f2fp8(acc[ct][r]);
        }
    }
}

// ---------------- FUSED gather + next-layer GEMM (256 thr, 32 nodes/block, W from L2) ----------------
__global__ __launch_bounds__(256) void fused_gather_gemm_kernel(
        const unsigned char* __restrict__ Hin,
        const int* __restrict__ rowptr,
        const long long* __restrict__ csr_rec,
        const float* __restrict__ selfw,
        const float* __restrict__ bias,
        const unsigned short* __restrict__ Wfrag,
        unsigned char* __restrict__ Hout, int n) {
    __shared__ unsigned short agg[32][136];  // 32 rows x 128 bf16, +8 pad (8.7 KB)
    int node0 = blockIdx.x * 32;
    int nl   = threadIdx.x >> 3;         // node-local 0..31
    int node = node0 + nl;
    int lane = threadIdx.x & 7;          // feature segment [lane*16, lane*16+16)
    if (node < n) {
        float acc[16];
        {
            uint4 sv = *reinterpret_cast<const uint4*>(Hin + (size_t)node * HIDF + lane * 16);
            const unsigned* svw = reinterpret_cast<const unsigned*>(&sv);
            float sw = selfw[node];
            #pragma unroll
            for (int d = 0; d < 4; ++d) {
                f32x2 lo = __builtin_amdgcn_cvt_pk_f32_fp8((int)svw[d], false);
                f32x2 hi = __builtin_amdgcn_cvt_pk_f32_fp8((int)svw[d], true);
                acc[d * 4 + 0] = lo[0] * sw; acc[d * 4 + 1] = lo[1] * sw;
                acc[d * 4 + 2] = hi[0] * sw; acc[d * 4 + 3] = hi[1] * sw;
            }
        }
        int beg = rowptr[node], end = rowptr[node + 1];
        int nfull = (end - beg) >> 3;
        int base = beg;
        for (int fb = 0; fb < nfull; ++fb, base += 8) {
            long long rec = csr_rec[base + lane];
            uint4 v[8];
            float w[8];
            #pragma unroll
            for (int j = 0; j < 8; ++j) {                    // 8 independent row loads in flight
                long long r = __shfl(rec, j, 8);
                int sn = (int)(unsigned)(r & 0xffffffffLL);
                w[j] = __int_as_float((int)(r >> 32));
                v[j] = *reinterpret_cast<const uint4*>(Hin + (size_t)sn * HIDF + lane * 16);
            }
            #pragma unroll
            for (int j = 0; j < 8; ++j) {
                const unsigned* vw = reinterpret_cast<const unsigned*>(&v[j]);
                #pragma unroll
                for (int d = 0; d < 4; ++d) {
                    f32x2 lo = __builtin_amdgcn_cvt_pk_f32_fp8((int)vw[d], false);
                    f32x2 hi = __builtin_amdgcn_cvt_pk_f32_fp8((int)vw[d], true);
                    acc[d * 4 + 0] += lo[0] * w[j]; acc[d * 4 + 1] += lo[1] * w[j];
                    acc[d * 4 + 2] += hi[0] * w[j]; acc[d * 4 + 3] += hi[1] * w[j];
                }
            }
        }
        int m = end - base;
        if (m > 0) {
            long long rec = (base + lane < end) ? csr_rec[base + lane] : 0;
            for (int j = 0; j < m; ++j) {
                long long r = __shfl(rec, j, 8);
                int sn = (int)(unsigned)(r & 0xffffffffLL);
                float w = __int_as_float((int)(r >> 32));
                uint4 v = *reinterpret_cast<const uint4*>(Hin + (size_t)sn * HIDF + lane * 16);
                const unsigned* vw = reinterpret_cast<const unsigned*>(&v);
                #pragma unroll
                for (int d = 0; d < 4; ++d) {
                    f32x2 lo = __builtin_amdgcn_cvt_pk_f32_fp8((int)vw[d], false);
                    f32x2 hi = __builtin_amdgcn_cvt_pk_f32_fp8((int)vw[d], true);
                    acc[d * 4 + 0] += lo[0] * w; acc[d * 4 + 1] += lo[1] * w;
                    acc[d * 4 + 2] += hi[0] * w; acc[d * 4 + 3] += hi[1] * w;
                }
            }
        }
        // bias + relu (f32, single round) -> bf16 A-tile
        #pragma unroll
        for (int i = 0; i < 16; ++i) {
            float vb = acc[i] + bias[lane * 16 + i];
            agg[nl][lane * 16 + i] = f2b(fmaxf(vb, 0.f));
        }
    } else {
        #pragma unroll
        for (int i = 0; i < 16; ++i) agg[nl][lane * 16 + i] = 0;
    }
    __syncthreads();
    // Phase B: MFMA over 32x128 tile. wave wv: row tile mt = wv>>1 (16 rows), col tiles ct0..ct0+3
    int wv = threadIdx.x >> 6;
    int l  = threadIdx.x & 63;
    int mt  = wv >> 1;                   // 0..1
    int ct0 = (wv & 1) * 4;
    int arow = mt * 16 + (l & 15);
    int koff = (l >> 4) * 8;
    f32x4 acc4[4] = {};
    #pragma unroll
    for (int kt = 0; kt < 4; ++kt) {
        int kbase = kt * 32 + koff;
        bf16x8 a = *reinterpret_cast<bf16x8*>(&agg[arow][kbase]);
        #pragma unroll
        for (int c = 0; c < 4; ++c) {
            int ct = ct0 + c;
            bf16x8 b = *reinterpret_cast<const bf16x8*>(&Wfrag[((kt * 8 + ct) * 64 + l) * 8]);
            acc4[c] = __builtin_amdgcn_mfma_f32_16x16x32_bf16(a, b, acc4[c], 0, 0, 0);
        }
    }
    int rloc = mt * 16 + ((l >> 4) << 2);
    int cbase = l & 15;
    #pragma unroll
    for (int c = 0; c < 4; ++c) {
        int ct = ct0 + c;
        #pragma unroll
        for (int r = 0; r < 4; ++r) {
            int gr = node0 + rloc + r;
            if (gr < n) Hout[(size_t)gr * HIDF + ct * 16 + cbase] = f2fp8(acc4[c][r]);
        }
    }
}

// ---------------- FUSED final gather + mean pool + centroid head: one block per graph ----------------
__device__ __forceinline__ int lower_bound_i(const int* __restrict__ a, int n, int key) {
    int lo = 0, hi = n;
    while (lo < hi) { int mid = (lo + hi) >> 1; if (a[mid] < key) lo = mid + 1; else hi = mid; }
    return lo;
}

__global__ __launch_bounds__(512) void gather_pool_final_kernel(
        const unsigned char* __restrict__ Hin,
        const int* __restrict__ rowptr,
        const long long* __restrict__ csr_rec,
        const float* __restrict__ selfw,
        const int* __restrict__ batch,
        const float* __restrict__ b3,
        const float* __restrict__ centroids,
        const float* __restrict__ std_scale,
        const float* __restrict__ ac_temp,
        float* __restrict__ out, int n) {
    __shared__ float part[64][HIDF];   // 32 KB partial sums
    __shared__ float gm[HIDF];
    int b = blockIdx.x;
    int grp  = threadIdx.x >> 3;       // group 0..63
    int lane = threadIdx.x & 7;        // feature segment [lane*16, lane*16+16)
    int s = lower_bound_i(batch, n, b);
    int e = lower_bound_i(batch, n, b + 1);
    float acc[16];
    #pragma unroll
    for (int i = 0; i < 16; ++i) acc[i] = 0.f;
    for (int node = s + grp; node < e; node += 64) {
        float t[16];
        {
            uint4 sv = *reinterpret_cast<const uint4*>(Hin + (size_t)node * HIDF + lane * 16);
            const unsigned* svw = reinterpret_cast<const unsigned*>(&sv);
            float sw = selfw[node];
            #pragma unroll
            for (int d = 0; d < 4; ++d) {
                f32x2 lo = __builtin_amdgcn_cvt_pk_f32_fp8((int)svw[d], false);
                f32x2 hi = __builtin_amdgcn_cvt_pk_f32_fp8((int)svw[d], true);
                t[d * 4 + 0] = lo[0] * sw; t[d * 4 + 1] = lo[1] * sw;
                t[d * 4 + 2] = hi[0] * sw; t[d * 4 + 3] = hi[1] * sw;
            }
        }
        int beg = rowptr[node], end = rowptr[node + 1];
        int nfull = (end - beg) >> 3;
        int base = beg;
        for (int fb = 0; fb < nfull; ++fb, base += 8) {
            long long rec = csr_rec[base + lane];
            uint4 v[8];
            float w[8];
            #pragma unroll
            for (int j = 0; j < 8; ++j) {
                long long r = __shfl(rec, j, 8);
                int sn = (int)(unsigned)(r & 0xffffffffLL);
                w[j] = __int_as_float((int)(r >> 32));
                v[j] = *reinterpret_cast<const uint4*>(Hin + (size_t)sn * HIDF + lane * 16);
            }
            #pragma unroll
            for (int j = 0; j < 8; ++j) {
                const unsigned* vw = reinterpret_cast<const unsigned*>(&v[j]);
                #pragma unroll
                for (int d = 0; d < 4; ++d) {
                    f32x2 lo = __builtin_amdgcn_cvt_pk_f32_fp8((int)vw[d], false);
                    f32x2 hi = __builtin_amdgcn_cvt_pk_f32_fp8((int)vw[d], true);
                    t[d * 4 + 0] += lo[0] * w[j]; t[d * 4 + 1] += lo[1] * w[j];
                    t[d * 4 + 2] += hi[0] * w[j]; t[d * 4 + 3] += hi[1] * w[j];
                }
            }
        }
        int m = end - base;
        if (m > 0) {
            long long rec = (base + lane < end) ? csr_rec[base + lane] : 0;
            for (int j = 0; j < m; ++j) {
                long long r = __shfl(rec, j, 8);
                int sn = (int)(unsigned)(r & 0xffffffffLL);
                float w = __int_as_float((int)(r >> 32));
                uint4 v = *reinterpret_cast<const uint4*>(Hin + (size_t)sn * HIDF + lane * 16);
                const unsigned* vw = reinterpret_cast<const unsigned*>(&v);
                #pragma unroll
                for (int d = 0; d < 4; ++d) {
                    f32x2 lo = __builtin_amdgcn_cvt_pk_f32_fp8((int)vw[d], false);
                    f32x2 hi = __builtin_amdgcn_cvt_pk_f32_fp8((int)vw[d], true);
                    t[d * 4 + 0] += lo[0] * w; t[d * 4 + 1] += lo[1] * w;
                    t[d * 4 + 2] += hi[0] * w; t[d * 4 + 3] += hi[1] * w;
                }
            }
        }
        #pragma unroll
        for (int i = 0; i < 16; ++i) acc[i] += t[i];
    }
    #pragma unroll
    for (int i = 0; i < 16; ++i) part[grp][lane * 16 + i] = acc[i];
    __syncthreads();
    if (threadIdx.x < HIDF) {
        int f = threadIdx.x;
        float sum = 0.f;
        #pragma unroll 8
        for (int g = 0; g < 64; ++g) sum += part[g][f];
        float cnt = fmaxf((float)(e - s), 1.0f);
        gm[f] = sum / cnt + b3[f];
    }
    __syncthreads();
    if (threadIdx.x < 64) {
        int l = threadIdx.x;
        float g0 = gm[l];
        float g1 = gm[64 + l];
        float mind = 1e30f;
        for (int c = 0; c < NCLS; ++c) {
            float dd[2];
            #pragma unroll
            for (int cent = 0; cent < 2; ++cent) {
                const float* cp = &centroids[(c * 2 + cent) * HIDF];
                float df0 = cp[l] - g0;
                float df1 = cp[64 + l] - g1;
                float p = df0 * df0 + df1 * df1;
                #pragma unroll
                for (int off = 32; off > 0; off >>= 1) p += __shfl_xor(p, off);
                dd[cent] = p;
            }
            float dist = fminf(sqrtf(dd[0]), sqrtf(dd[1]));
            mind = fminf(mind, dist);
            if (l == 0) out[b * NCLS + c] = -dist;
        }
        if (l == 0) {
            float ss = std_scale[0];
            float clipped = fminf(fmaxf(ss, 0.0f), 5.0f);
            float max_ac = 1.0f + clipped * 0.0f;      // RUNNING_MEAN=1, sqrt(RUNNING_VAR)=0
            float accept = max_ac - mind;
            float soft = 1.0f / (1.0f + expf(-accept / ac_temp[0]));
            out[NGR * NCLS + b] = soft;
        }
    }
}

// ---------------- launch ----------------
extern "C" void kernel_launch(void* const* d_in, const int* in_sizes, int n_in,
                              void* d_out, int out_size, void* d_ws, size_t ws_size,
                              hipStream_t stream) {
    const float* x         = (const float*)d_in[0];
    const int*   edge      = (const int*)d_in[1];
    const int*   batch     = (const int*)d_in[2];
    const float* W1        = (const float*)d_in[3];
    const float* b1        = (const float*)d_in[4];
    const float* W2        = (const float*)d_in[5];
    const float* b2        = (const float*)d_in[6];
    const float* W3        = (const float*)d_in[7];
    const float* b3        = (const float*)d_in[8];
    const float* centroids = (const float*)d_in[9];
    const float* std_scale = (const float*)d_in[10];
    const float* ac_temp   = (const float*)d_in[11];
    float* out = (float*)d_out;

    const int n  = NN;
    const int nE = in_sizes[1] / 2;
    const int* srcp = edge;
    const int* dstp = edge + nE;
    const int nch = (nE + CHSZ - 1) / CHSZ;

    // workspace layout (256B aligned)
    char* ws = (char*)d_ws;
    size_t off = 0;
    auto alloc = [&](size_t bytes) { void* p = ws + off; off = (off + bytes + 255) & ~(size_t)255; return p; };
    unsigned char*  hP = (unsigned char*) alloc((size_t)NN * HIDF);      // fp8 table (ping)
    unsigned char*  hQ = (unsigned char*) alloc((size_t)NN * HIDF);      // fp8 table (pong)
    unsigned short* Wf = (unsigned short*)alloc((size_t)3 * HIDF * HIDF * 2);
    float* dinv    = (float*)alloc((size_t)NN * 4);
    float* selfw   = (float*)alloc((size_t)NN * 4);
    int*   cnt     = (int*)  alloc((size_t)NN * 4);
    int*   rowptr  = (int*)  alloc((size_t)(NN + 1) * 4);
    long long* csr_rec  = (long long*)alloc((size_t)nE * 8);
    unsigned*  recs_bin = (unsigned*) alloc((size_t)nE * 4);
    int2*  cando   = (int2*) alloc((size_t)nch * NBKT * 8);
    int*   bktsum  = (int*)  alloc((size_t)NBKT * 4);
    int*   bktoff  = (int*)  alloc((size_t)NBKT * 4);

    // ---- weight prep + CSR build (CSR reused by all 3 layers) ----
    wprep_kernel<<<192, 256, 0, stream>>>(W1, W2, W3, Wf);
    bin_kernel<<<nch, 256, 0, stream>>>(srcp, dstp, recs_bin, cando, nE);
    bucket_count_kernel<<<NBKT, 512, 0, stream>>>(recs_bin, cando, cnt, bktsum, dinv, selfw, nch, n);
    scan_bkt_kernel<<<1, 512, 0, stream>>>(bktsum, bktoff, NBKT);
    bucket_fill_kernel<<<NBKT, 512, 0, stream>>>(recs_bin, cando, cnt, bktoff, dinv, rowptr, csr_rec, nch, n, nE);

    int gemm_blocks  = (n + 63) / 64;
    int fused_blocks = (n + 31) / 32;

    // layer 1 GEMM: x @ W1 -> hP (fp8)
    mfma_gemm_kernel<<<gemm_blocks, 256, 0, stream>>>(x, Wf, hP, n);
    // fused: gather(hP) -> +b1,relu -> @W2 -> hQ (fp8)
    fused_gather_gemm_kernel<<<fused_blocks, 256, 0, stream>>>(hP, rowptr, csr_rec, selfw, b1, Wf + 16384, hQ, n);
    // fused: gather(hQ) -> +b2,relu -> @W3 -> hP (fp8)
    fused_gather_gemm_kernel<<<fused_blocks, 256, 0, stream>>>(hQ, rowptr, csr_rec, selfw, b2, Wf + 32768, hP, n);
    // fused final gather + mean pool (+b3) + centroid head
    gather_pool_final_kernel<<<NGR, 512, 0, stream>>>(hP, rowptr, csr_rec, selfw, batch, b3,
                                                      centroids, std_scale, ac_temp, out, n);
}

// Round 21
// 219.034 us; speedup vs baseline: 1.1313x; 1.0322x over previous
//
#include <hip/hip_runtime.h>
#include <hip/hip_bf16.h>
#include <math.h>

#define NN 100000
#define NEDGE 1600000
#define HIDF 128
#define NCLS 18
#define NGR 512
#define CHSZ 2048                     // edges per bin chunk
#define NBKT 391                      // ceil(NN/256) buckets of 256 nodes
#define SRCM 0x1FFFF                  // 17-bit src mask (NN < 2^17)

using bf16x8  = __attribute__((ext_vector_type(8))) short;   // 8 bf16 in 4 VGPRs
using ushort8 = __attribute__((ext_vector_type(8))) unsigned short;
using f32x4   = __attribute__((ext_vector_type(4))) float;
using f32x2   = __attribute__((ext_vector_type(2))) float;

__device__ __forceinline__ float b2f(unsigned short u) {
    return __uint_as_float(((unsigned)u) << 16);
}
__device__ __forceinline__ unsigned short f2b(float f) {   // round-to-nearest-even
    unsigned u = __float_as_uint(f);
    unsigned r = (u + 0x7fffu + ((u >> 16) & 1u)) >> 16;
    return (unsigned short)r;
}
__device__ __forceinline__ unsigned char f2fp8(float f) {  // f32 -> OCP e4m3 (HW cvt)
    int p = __builtin_amdgcn_cvt_pk_fp8_f32(f, f, 0, false);
    return (unsigned char)(p & 0xff);
}

// ---------------- phase 1: bin edges into 256-node buckets; 4-B bin records (dst_low8<<17 | src) ----------------
__global__ __launch_bounds__(256) void bin_kernel(const int* __restrict__ src,
                                                  const int* __restrict__ dst,
                                                  unsigned* __restrict__ recs_out,
                                                  int2* __restrict__ cando, int nE) {
    __shared__ int cnt[512];
    __shared__ int ssum[256];
    __shared__ unsigned recs[CHSZ];   // 8 KB
    int c = blockIdx.x;
    int t = threadIdx.x;
    cnt[t] = 0; cnt[t + 256] = 0;
    __syncthreads();
    int e0 = c * CHSZ;
    int nv = nE - e0; if (nv > CHSZ) nv = CHSZ;
    int s8[8], d8[8];
    #pragma unroll
    for (int i = 0; i < 8; i++) {
        int li = t + i * 256;
        bool ok = li < nv;
        s8[i] = ok ? src[e0 + li] : -1;
        d8[i] = ok ? dst[e0 + li] : -1;
        if (ok) atomicAdd(&cnt[d8[i] >> 8], 1);
    }
    __syncthreads();
    int a = cnt[2 * t], b_ = cnt[2 * t + 1];
    ssum[t] = a + b_;
    __syncthreads();
    for (int off = 1; off < 256; off <<= 1) {       // Hillis-Steele inclusive over 256 pair-sums
        int v = (t >= off) ? ssum[t - off] : 0;
        __syncthreads();
        ssum[t] += v;
        __syncthreads();
    }
    int excl = ssum[t] - (a + b_);
    if (2 * t < NBKT)     cando[(size_t)c * NBKT + 2 * t]     = make_int2(a, excl);
    if (2 * t + 1 < NBKT) cando[(size_t)c * NBKT + 2 * t + 1] = make_int2(b_, excl + a);
    __syncthreads();
    cnt[2 * t] = excl; cnt[2 * t + 1] = excl + a;    // reuse as cursors
    __syncthreads();
    #pragma unroll
    for (int i = 0; i < 8; i++) {
        if (d8[i] >= 0) {
            int pos = atomicAdd(&cnt[d8[i] >> 8], 1);
            recs[pos] = ((unsigned)(d8[i] & 255) << 17) | (unsigned)s8[i];
        }
    }
    __syncthreads();
    for (int j = t; j < nv; j += 256)
        recs_out[(size_t)e0 + j] = recs[j];          // fully coalesced 4B stores
}

// ---------------- per-bucket degree count + node prep + bucket totals (fused) ----------------
__global__ __launch_bounds__(512) void bucket_count_kernel(const unsigned* __restrict__ recs_bin,
                                                           const int2* __restrict__ cando,
                                                           int* __restrict__ cnt,
                                                           int* __restrict__ bktsum,
                                                           float* __restrict__ dinv,
                                                           float* __restrict__ selfw,
                                                           int nch, int n) {
    __shared__ int c256[256];
    __shared__ int wsum[4];
    int b = blockIdx.x;
    int t = threadIdx.x;
    if (t < 256) c256[t] = 0;
    __syncthreads();
    for (int c = t; c < nch; c += 512) {
        int2 co = cando[(size_t)c * NBKT + b];
        size_t base = (size_t)c * CHSZ + co.y;
        for (int k = 0; k < co.x; ++k) {
            unsigned rec = recs_bin[base + k];
            atomicAdd(&c256[rec >> 17], 1);         // dst_low8
        }
    }
    __syncthreads();
    int node = (b << 8) + t;
    int cv = 0;
    if (t < 256) {
        cv = c256[t];
        if (node < n) {
            cnt[node] = cv;
            float deg = (float)cv + 1.0f;   // +1 self loop
            dinv[node]  = rsqrtf(deg);
            selfw[node] = 1.0f / deg;
        }
    }
    if (t < 256) {
        int s = cv;
        #pragma unroll
        for (int off = 32; off > 0; off >>= 1) s += __shfl_down(s, off);
        if ((t & 63) == 0) wsum[t >> 6] = s;
    }
    __syncthreads();
    if (t == 0) bktsum[b] = wsum[0] + wsum[1] + wsum[2] + wsum[3];
}

// ---------------- scan of 391 bucket sums (one tiny block) ----------------
__global__ __launch_bounds__(512) void scan_bkt_kernel(const int* __restrict__ bktsum,
                                                       int* __restrict__ bktoff, int nb) {
    __shared__ int t512[512];
    int t = threadIdx.x;
    t512[t] = (t < nb) ? bktsum[t] : 0;
    __syncthreads();
    for (int off = 1; off < 512; off <<= 1) {
        int v = (t >= off) ? t512[t - off] : 0;
        __syncthreads();
        t512[t] += v;
        __syncthreads();
    }
    if (t < nb) bktoff[t] = (t == 0) ? 0 : t512[t - 1];
}

// ---------------- phase 2: per-bucket CSR fill (8-B records {f32 w, src}) + rowptr ----------------
__global__ __launch_bounds__(512) void bucket_fill_kernel(const unsigned* __restrict__ recs_bin,
                                                          const int2* __restrict__ cando,
                                                          const int* __restrict__ cnt,
                                                          const int* __restrict__ bktoff,
                                                          const float* __restrict__ dinv,
                                                          int* __restrict__ rowptr,
                                                          long long* __restrict__ csr_rec,
                                                          int nch, int n, int nE) {
    __shared__ int cur[256];
    __shared__ int scn[256];
    int b = blockIdx.x;
    int node0 = b << 8;
    int t = threadIdx.x;
    int cv = 0;
    if (t < 256) {
        int nd = node0 + t;
        cv = (nd < n) ? cnt[nd] : 0;
        scn[t] = cv;
    }
    __syncthreads();
    for (int off = 1; off < 256; off <<= 1) {     // inclusive scan over this bucket's 256 counts
        int v = (t < 256 && t >= off) ? scn[t - off] : 0;
        __syncthreads();
        if (t < 256) scn[t] += v;
        __syncthreads();
    }
    if (t < 256) {
        int nd = node0 + t;
        int excl = bktoff[b] + scn[t] - cv;       // exclusive prefix = global row start
        if (nd < n) { rowptr[nd] = excl; cur[t] = excl; }
    }
    if (b == NBKT - 1 && t == 0) rowptr[n] = nE;
    __syncthreads();
    for (int c = t; c < nch; c += 512) {
        int2 co = cando[(size_t)c * NBKT + b];
        size_t base = (size_t)c * CHSZ + co.y;
        for (int k = 0; k < co.x; ++k) {
            unsigned rec = recs_bin[base + k];
            int dlow = rec >> 17;
            int s = rec & SRCM;
            int d = node0 + dlow;
            float w = dinv[s] * dinv[d];
            int pos = atomicAdd(&cur[dlow], 1);
            csr_rec[pos] = ((long long)__float_as_int(w) << 32) | (unsigned)s;
        }
    }
}

// ---------------- weight prep: pack W (f32 row-major 128x128) into B-fragment-linear bf16 ----------------
__global__ __launch_bounds__(256) void wprep_kernel(const float* __restrict__ W1,
                                                    const float* __restrict__ W2,
                                                    const float* __restrict__ W3,
                                                    unsigned short* __restrict__ Wf) {
    int gid = blockIdx.x * 256 + threadIdx.x;   // 0..49151
    int w = gid >> 14;
    int o = gid & 16383;
    int j = o & 7, lane = (o >> 3) & 63, ct = (o >> 9) & 7, kt = o >> 12;
    int rk = kt * 32 + (lane >> 4) * 8 + j;
    int col = ct * 16 + (lane & 15);
    const float* W = (w == 0) ? W1 : ((w == 1) ? W2 : W3);
    Wf[gid] = f2b(W[rk * HIDF + col]);
}

// ---------------- MFMA GEMM (layer 1): Hfp8 = x @ W1  (f32 in, fp8 out) ----------------
__global__ __launch_bounds__(256) void mfma_gemm_kernel(const float* __restrict__ X,
                                                        const unsigned short* __restrict__ Wfrag,
                                                        unsigned char* __restrict__ Hfp8, int n) {
    __shared__ unsigned short wl[16384];   // 32 KB: full 128x128 bf16 W in fragment-linear layout
    {
        const uint4* wsrc = reinterpret_cast<const uint4*>(Wfrag);
        uint4* wdst = reinterpret_cast<uint4*>(wl);
        for (int i = threadIdx.x; i < 2048; i += 256) wdst[i] = wsrc[i];
    }
    __syncthreads();

    int wv = threadIdx.x >> 6;          // wave 0..3
    int l  = threadIdx.x & 63;          // lane
    int row = blockIdx.x * 64 + wv * 16 + (l & 15);
    int koff = (l >> 4) * 8;
    bool rowok = row < n;

    f32x4 acc[8] = {};
    #pragma unroll
    for (int kt = 0; kt < 4; ++kt) {
        int kbase = kt * 32 + koff;
        bf16x8 a;
        float4 x0 = {0,0,0,0}, x1 = {0,0,0,0};
        if (rowok) {
            x0 = *reinterpret_cast<const float4*>(&X[(size_t)row * HIDF + kbase]);
            x1 = *reinterpret_cast<const float4*>(&X[(size_t)row * HIDF + kbase + 4]);
        }
        a[0] = (short)f2b(x0.x); a[1] = (short)f2b(x0.y);
        a[2] = (short)f2b(x0.z); a[3] = (short)f2b(x0.w);
        a[4] = (short)f2b(x1.x); a[5] = (short)f2b(x1.y);
        a[6] = (short)f2b(x1.z); a[7] = (short)f2b(x1.w);
        #pragma unroll
        for (int ct = 0; ct < 8; ++ct) {
            bf16x8 b = *reinterpret_cast<bf16x8*>(&wl[((kt * 8 + ct) * 64 + l) * 8]);
            acc[ct] = __builtin_amdgcn_mfma_f32_16x16x32_bf16(a, b, acc[ct], 0, 0, 0);
        }
    }
    int rbase = blockIdx.x * 64 + wv * 16 + ((l >> 4) << 2);
    int cbase = l & 15;
    #pragma unroll
    for (int ct = 0; ct < 8; ++ct) {
        #pragma unroll
        for (int r = 0; r < 4; ++r) {
            int gr = rbase + r;
            if (gr < n) Hfp8[(size_t)gr * HIDF + ct * 16 + cbase] = f2fp8(acc[ct][r]);
        }
    }
}

// ---------------- FUSED gather + next-layer GEMM (256 thr, 32 nodes/block, W from L2) ----------------
__global__ __launch_bounds__(256) void fused_gather_gemm_kernel(
        const unsigned char* __restrict__ Hin,
        const int* __restrict__ rowptr,
        const long long* __restrict__ csr_rec,
        const float* __restrict__ selfw,
        const float* __restrict__ bias,
        const unsigned short* __restrict__ Wfrag,
        unsigned char* __restrict__ Hout, int n) {
    __shared__ unsigned short agg[32][136];  // 32 rows x 128 bf16, +8 pad (8.7 KB)
    int node0 = blockIdx.x * 32;
    int nl   = threadIdx.x >> 3;         // node-local 0..31
    int node = node0 + nl;
    int lane = threadIdx.x & 7;          // feature segment [lane*16, lane*16+16)
    if (node < n) {
        float acc[16];
        {
            uint4 sv = *reinterpret_cast<const uint4*>(Hin + (size_t)node * HIDF + lane * 16);
            const unsigned* svw = reinterpret_cast<const unsigned*>(&sv);
            float sw = selfw[node];
            #pragma unroll
            for (int d = 0; d < 4; ++d) {
                f32x2 lo = __builtin_amdgcn_cvt_pk_f32_fp8((int)svw[d], false);
                f32x2 hi = __builtin_amdgcn_cvt_pk_f32_fp8((int)svw[d], true);
                acc[d * 4 + 0] = lo[0] * sw; acc[d * 4 + 1] = lo[1] * sw;
                acc[d * 4 + 2] = hi[0] * sw; acc[d * 4 + 3] = hi[1] * sw;
            }
        }
        int beg = rowptr[node], end = rowptr[node + 1];
        int nfull = (end - beg) >> 3;
        int base = beg;
        for (int fb = 0; fb < nfull; ++fb, base += 8) {
            long long rec = csr_rec[base + lane];
            uint4 v[8];
            float w[8];
            #pragma unroll
            for (int j = 0; j < 8; ++j) {                    // 8 independent row loads in flight
                long long r = __shfl(rec, j, 8);
                int sn = (int)(unsigned)(r & 0xffffffffLL);
                w[j] = __int_as_float((int)(r >> 32));
                v[j] = *reinterpret_cast<const uint4*>(Hin + (size_t)sn * HIDF + lane * 16);
            }
            #pragma unroll
            for (int j = 0; j < 8; ++j) {
                const unsigned* vw = reinterpret_cast<const unsigned*>(&v[j]);
                #pragma unroll
                for (int d = 0; d < 4; ++d) {
                    f32x2 lo = __builtin_amdgcn_cvt_pk_f32_fp8((int)vw[d], false);
                    f32x2 hi = __builtin_amdgcn_cvt_pk_f32_fp8((int)vw[d], true);
                    acc[d * 4 + 0] += lo[0] * w[j]; acc[d * 4 + 1] += lo[1] * w[j];
                    acc[d * 4 + 2] += hi[0] * w[j]; acc[d * 4 + 3] += hi[1] * w[j];
                }
            }
        }
        int m = end - base;
        if (m > 0) {
            long long rec = (base + lane < end) ? csr_rec[base + lane] : 0;
            for (int j = 0; j < m; ++j) {
                long long r = __shfl(rec, j, 8);
                int sn = (int)(unsigned)(r & 0xffffffffLL);
                float w = __int_as_float((int)(r >> 32));
                uint4 v = *reinterpret_cast<const uint4*>(Hin + (size_t)sn * HIDF + lane * 16);
                const unsigned* vw = reinterpret_cast<const unsigned*>(&v);
                #pragma unroll
                for (int d = 0; d < 4; ++d) {
                    f32x2 lo = __builtin_amdgcn_cvt_pk_f32_fp8((int)vw[d], false);
                    f32x2 hi = __builtin_amdgcn_cvt_pk_f32_fp8((int)vw[d], true);
                    acc[d * 4 + 0] += lo[0] * w; acc[d * 4 + 1] += lo[1] * w;
                    acc[d * 4 + 2] += hi[0] * w; acc[d * 4 + 3] += hi[1] * w;
                }
            }
        }
        // bias + relu (f32, single round) -> bf16 A-tile
        #pragma unroll
        for (int i = 0; i < 16; ++i) {
            float vb = acc[i] + bias[lane * 16 + i];
            agg[nl][lane * 16 + i] = f2b(fmaxf(vb, 0.f));
        }
    } else {
        #pragma unroll
        for (int i = 0; i < 16; ++i) agg[nl][lane * 16 + i] = 0;
    }
    __syncthreads();
    // Phase B: MFMA over 32x128 tile. wave wv: row tile mt = wv>>1 (16 rows), col tiles ct0..ct0+3
    int wv = threadIdx.x >> 6;
    int l  = threadIdx.x & 63;
    int mt  = wv >> 1;                   // 0..1
    int ct0 = (wv & 1) * 4;
    int arow = mt * 16 + (l & 15);
    int koff = (l >> 4) * 8;
    f32x4 acc4[4] = {};
    #pragma unroll
    for (int kt = 0; kt < 4; ++kt) {
        int kbase = kt * 32 + koff;
        bf16x8 a = *reinterpret_cast<bf16x8*>(&agg[arow][kbase]);
        #pragma unroll
        for (int c = 0; c < 4; ++c) {
            int ct = ct0 + c;
            bf16x8 b = *reinterpret_cast<const bf16x8*>(&Wfrag[((kt * 8 + ct) * 64 + l) * 8]);
            acc4[c] = __builtin_amdgcn_mfma_f32_16x16x32_bf16(a, b, acc4[c], 0, 0, 0);
        }
    }
    int rloc = mt * 16 + ((l >> 4) << 2);
    int cbase = l & 15;
    #pragma unroll
    for (int c = 0; c < 4; ++c) {
        int ct = ct0 + c;
        #pragma unroll
        for (int r = 0; r < 4; ++r) {
            int gr = node0 + rloc + r;
            if (gr < n) Hout[(size_t)gr * HIDF + ct * 16 + cbase] = f2fp8(acc4[c][r]);
        }
    }
}

// ---------------- FUSED final: EDGE-PARALLEL gather + mean pool + centroid head ----------------
// Graph b's nodes are contiguous [s,e) -> its CSR rows form one contiguous edge range
// [rowptr[s], rowptr[e]). pool_sum = sum_{d in [s,e)} selfw[d]*h[d]  (coalesced sweep)
//                                  + sum_{k in [rowptr[s],rowptr[e])} w[k]*h[src[k]]  (flat edge loop)
// No per-node chains -> perfect load balance, 8-edge pipelined batches throughout.
__device__ __forceinline__ int lower_bound_i(const int* __restrict__ a, int n, int key) {
    int lo = 0, hi = n;
    while (lo < hi) { int mid = (lo + hi) >> 1; if (a[mid] < key) lo = mid + 1; else hi = mid; }
    return lo;
}

__global__ __launch_bounds__(512) void gather_pool_final_kernel(
        const unsigned char* __restrict__ Hin,
        const int* __restrict__ rowptr,
        const long long* __restrict__ csr_rec,
        const float* __restrict__ selfw,
        const int* __restrict__ batch,
        const float* __restrict__ b3,
        const float* __restrict__ centroids,
        const float* __restrict__ std_scale,
        const float* __restrict__ ac_temp,
        float* __restrict__ out, int n) {
    __shared__ float part[64][HIDF];   // 32 KB partial sums
    __shared__ float gm[HIDF];
    int b = blockIdx.x;
    int grp  = threadIdx.x >> 3;       // group 0..63
    int lane = threadIdx.x & 7;        // feature segment [lane*16, lane*16+16)
    int s = lower_bound_i(batch, n, b);
    int e = lower_bound_i(batch, n, b + 1);
    float acc[16];
    #pragma unroll
    for (int i = 0; i < 16; ++i) acc[i] = 0.f;

    // ---- self-loop term: coalesced sweep over graph's own rows ----
    for (int node = s + grp; node < e; node += 64) {
        uint4 sv = *reinterpret_cast<const uint4*>(Hin + (size_t)node * HIDF + lane * 16);
        const unsigned* svw = reinterpret_cast<const unsigned*>(&sv);
        float sw = selfw[node];
        #pragma unroll
        for (int d = 0; d < 4; ++d) {
            f32x2 lo = __builtin_amdgcn_cvt_pk_f32_fp8((int)svw[d], false);
            f32x2 hi = __builtin_amdgcn_cvt_pk_f32_fp8((int)svw[d], true);
            acc[d * 4 + 0] += lo[0] * sw; acc[d * 4 + 1] += lo[1] * sw;
            acc[d * 4 + 2] += hi[0] * sw; acc[d * 4 + 3] += hi[1] * sw;
        }
    }

    // ---- edge term: flat edge-parallel loop over the graph's contiguous CSR range ----
    int estart = rowptr[s], eend = rowptr[e];
    for (int base = estart + grp * 8; base < eend; base += 512) {
        int m = eend - base; if (m > 8) m = 8;
        if (m == 8) {
            long long rec = csr_rec[base + lane];            // 64B coalesced per group
            uint4 v[8];
            float w[8];
            #pragma unroll
            for (int j = 0; j < 8; ++j) {                    // 8 independent row loads in flight
                long long r = __shfl(rec, j, 8);
                int sn = (int)(unsigned)(r & 0xffffffffLL);
                w[j] = __int_as_float((int)(r >> 32));
                v[j] = *reinterpret_cast<const uint4*>(Hin + (size_t)sn * HIDF + lane * 16);
            }
            #pragma unroll
            for (int j = 0; j < 8; ++j) {
                const unsigned* vw = reinterpret_cast<const unsigned*>(&v[j]);
                #pragma unroll
                for (int d = 0; d < 4; ++d) {
                    f32x2 lo = __builtin_amdgcn_cvt_pk_f32_fp8((int)vw[d], false);
                    f32x2 hi = __builtin_amdgcn_cvt_pk_f32_fp8((int)vw[d], true);
                    acc[d * 4 + 0] += lo[0] * w[j]; acc[d * 4 + 1] += lo[1] * w[j];
                    acc[d * 4 + 2] += hi[0] * w[j]; acc[d * 4 + 3] += hi[1] * w[j];
                }
            }
        } else {
            long long rec = (base + lane < eend) ? csr_rec[base + lane] : 0;
            for (int j = 0; j < m; ++j) {
                long long r = __shfl(rec, j, 8);
                int sn = (int)(unsigned)(r & 0xffffffffLL);
                float w = __int_as_float((int)(r >> 32));
                uint4 v = *reinterpret_cast<const uint4*>(Hin + (size_t)sn * HIDF + lane * 16);
                const unsigned* vw = reinterpret_cast<const unsigned*>(&v);
                #pragma unroll
                for (int d = 0; d < 4; ++d) {
                    f32x2 lo = __builtin_amdgcn_cvt_pk_f32_fp8((int)vw[d], false);
                    f32x2 hi = __builtin_amdgcn_cvt_pk_f32_fp8((int)vw[d], true);
                    acc[d * 4 + 0] += lo[0] * w; acc[d * 4 + 1] += lo[1] * w;
                    acc[d * 4 + 2] += hi[0] * w; acc[d * 4 + 3] += hi[1] * w;
                }
            }
        }
    }

    #pragma unroll
    for (int i = 0; i < 16; ++i) part[grp][lane * 16 + i] = acc[i];
    __syncthreads();
    if (threadIdx.x < HIDF) {
        int f = threadIdx.x;
        float sum = 0.f;
        #pragma unroll 8
        for (int g = 0; g < 64; ++g) sum += part[g][f];
        float cnt = fmaxf((float)(e - s), 1.0f);
        gm[f] = sum / cnt + b3[f];
    }
    __syncthreads();
    if (threadIdx.x < 64) {
        int l = threadIdx.x;
        float g0 = gm[l];
        float g1 = gm[64 + l];
        float mind = 1e30f;
        for (int c = 0; c < NCLS; ++c) {
            float dd[2];
            #pragma unroll
            for (int cent = 0; cent < 2; ++cent) {
                const float* cp = &centroids[(c * 2 + cent) * HIDF];
                float df0 = cp[l] - g0;
                float df1 = cp[64 + l] - g1;
                float p = df0 * df0 + df1 * df1;
                #pragma unroll
                for (int off = 32; off > 0; off >>= 1) p += __shfl_xor(p, off);
                dd[cent] = p;
            }
            float dist = fminf(sqrtf(dd[0]), sqrtf(dd[1]));
            mind = fminf(mind, dist);
            if (l == 0) out[b * NCLS + c] = -dist;
        }
        if (l == 0) {
            float ss = std_scale[0];
            float clipped = fminf(fmaxf(ss, 0.0f), 5.0f);
            float max_ac = 1.0f + clipped * 0.0f;      // RUNNING_MEAN=1, sqrt(RUNNING_VAR)=0
            float accept = max_ac - mind;
            float soft = 1.0f / (1.0f + expf(-accept / ac_temp[0]));
            out[NGR * NCLS + b] = soft;
        }
    }
}

// ---------------- launch ----------------
extern "C" void kernel_launch(void* const* d_in, const int* in_sizes, int n_in,
                              void* d_out, int out_size, void* d_ws, size_t ws_size,
                              hipStream_t stream) {
    const float* x         = (const float*)d_in[0];
    const int*   edge      = (const int*)d_in[1];
    const int*   batch     = (const int*)d_in[2];
    const float* W1        = (const float*)d_in[3];
    const float* b1        = (const float*)d_in[4];
    const float* W2        = (const float*)d_in[5];
    const float* b2        = (const float*)d_in[6];
    const float* W3        = (const float*)d_in[7];
    const float* b3        = (const float*)d_in[8];
    const float* centroids = (const float*)d_in[9];
    const float* std_scale = (const float*)d_in[10];
    const float* ac_temp   = (const float*)d_in[11];
    float* out = (float*)d_out;

    const int n  = NN;
    const int nE = in_sizes[1] / 2;
    const int* srcp = edge;
    const int* dstp = edge + nE;
    const int nch = (nE + CHSZ - 1) / CHSZ;

    // workspace layout (256B aligned)
    char* ws = (char*)d_ws;
    size_t off = 0;
    auto alloc = [&](size_t bytes) { void* p = ws + off; off = (off + bytes + 255) & ~(size_t)255; return p; };
    unsigned char*  hP = (unsigned char*) alloc((size_t)NN * HIDF);      // fp8 table (ping)
    unsigned char*  hQ = (unsigned char*) alloc((size_t)NN * HIDF);      // fp8 table (pong)
    unsigned short* Wf = (unsigned short*)alloc((size_t)3 * HIDF * HIDF * 2);
    float* dinv    = (float*)alloc((size_t)NN * 4);
    float* selfw   = (float*)alloc((size_t)NN * 4);
    int*   cnt     = (int*)  alloc((size_t)NN * 4);
    int*   rowptr  = (int*)  alloc((size_t)(NN + 1) * 4);
    long long* csr_rec  = (long long*)alloc((size_t)nE * 8);
    unsigned*  recs_bin = (unsigned*) alloc((size_t)nE * 4);
    int2*  cando   = (int2*) alloc((size_t)nch * NBKT * 8);
    int*   bktsum  = (int*)  alloc((size_t)NBKT * 4);
    int*   bktoff  = (int*)  alloc((size_t)NBKT * 4);

    // ---- weight prep + CSR build (CSR reused by all 3 layers) ----
    wprep_kernel<<<192, 256, 0, stream>>>(W1, W2, W3, Wf);
    bin_kernel<<<nch, 256, 0, stream>>>(srcp, dstp, recs_bin, cando, nE);
    bucket_count_kernel<<<NBKT, 512, 0, stream>>>(recs_bin, cando, cnt, bktsum, dinv, selfw, nch, n);
    scan_bkt_kernel<<<1, 512, 0, stream>>>(bktsum, bktoff, NBKT);
    bucket_fill_kernel<<<NBKT, 512, 0, stream>>>(recs_bin, cando, cnt, bktoff, dinv, rowptr, csr_rec, nch, n, nE);

    int gemm_blocks  = (n + 63) / 64;
    int fused_blocks = (n + 31) / 32;

    // layer 1 GEMM: x @ W1 -> hP (fp8)
    mfma_gemm_kernel<<<gemm_blocks, 256, 0, stream>>>(x, Wf, hP, n);
    // fused: gather(hP) -> +b1,relu -> @W2 -> hQ (fp8)
    fused_gather_gemm_kernel<<<fused_blocks, 256, 0, stream>>>(hP, rowptr, csr_rec, selfw, b1, Wf + 16384, hQ, n);
    // fused: gather(hQ) -> +b2,relu -> @W3 -> hP (fp8)
    fused_gather_gemm_kernel<<<fused_blocks, 256, 0, stream>>>(hQ, rowptr, csr_rec, selfw, b2, Wf + 32768, hP, n);
    // fused final: edge-parallel gather + mean pool (+b3) + centroid head
    gather_pool_final_kernel<<<NGR, 512, 0, stream>>>(hP, rowptr, csr_rec, selfw, batch, b3,
                                                      centroids, std_scale, ac_temp, out, n);
}